// Round 2
// baseline (215.571 us; speedup 1.0000x reference)
//
#include <hip/hip_runtime.h>

// ECConv: out = relu(concat(nf[:8192], mean_seg(relu(EF@We+be).reshape(E,64,64) @ h_src)) @ Wn + bn)
// Sizes: E=65536, N_SRC=32768, N_DST=8192, EDGE_IN=32, NODE_IN=64, HIDDEN=64, cols=4096
// R2: d0-split x4 (grid 256->1024, occupancy 10.7%->~45%), cnt fused into edge scatter,
//     Wn LDS-staged in final kernel.

typedef float f32x4 __attribute__((ext_vector_type(4)));
typedef __bf16 bf16x8 __attribute__((ext_vector_type(8)));
typedef __bf16 bf16x4 __attribute__((ext_vector_type(4)));

#define E_TOT   65536
#define NDST    8192
#define EP      264   // padded LDS row length (edges) for transposed h_src
#define DSPLIT  4     // d0 chunks per edge block

// ---------------- pack W_e (fp32 [32][4096]) into MFMA-B fragment order, bf16 ----------------
// Tile T = d0*4 + ht covers GEMM cols n = (ht*16 + c)*64 + d0, c=0..15 (16 h at fixed d).
// B frag for mfma_f32_16x16x32_bf16: lane l holds B[k = (l>>4)*8 + j][col = l&15], j=0..7.
__global__ void pack_kernel(const float* __restrict__ We, const float* __restrict__ be,
                            __bf16* __restrict__ Wp, float* __restrict__ bp) {
  int tid = blockIdx.x * 256 + threadIdx.x;       // 16384 threads
  int T = tid >> 6, l = tid & 63;
  int d0 = T >> 2, ht = T & 3;
  int c = l & 15, kg = l >> 4;
  int ncol = (ht * 16 + c) * 64 + d0;
  bf16x8 v;
#pragma unroll
  for (int j = 0; j < 8; ++j) {
    int k = kg * 8 + j;
    v[j] = (__bf16)We[k * 4096 + ncol];
  }
  *reinterpret_cast<bf16x8*>(Wp + tid * 8) = v;
  if (l < 16) bp[T * 16 + l] = be[(ht * 16 + l) * 64 + d0];
}

// ---------------- main fused edge kernel ----------------
// Block: 256 threads = 4 waves; covers 256 edges x 16 d0 values (chunk = blockIdx.x & 3).
// Per wave: 64 edges (4 A-frags), loop 16 d0 x 4 ht; epilogue relu(C)*h_src -> acc (partial
// over this block's d0 chunk); fp32 atomic scatter into msum. chunk==0 blocks also count.
__global__ __launch_bounds__(256, 4) void edge_kernel(
    const float* __restrict__ nf, const float* __restrict__ ef,
    const int* __restrict__ src, const int* __restrict__ dst,
    const __bf16* __restrict__ Wp, const float* __restrict__ bp,
    float* __restrict__ msum, float* __restrict__ cnt_g) {
  __shared__ __bf16 hs[16 * EP];   // transposed: hs[d_local][e_local], bf16, 8.4 KB
  const int t = threadIdx.x;
  const int chunk = blockIdx.x & (DSPLIT - 1);
  const int eblk = (blockIdx.x >> 2) << 8;
  const int d0base = chunk << 4;

  // stage h_src chunk = nf[src[e]][d0base..d0base+16) transposed into LDS
  {
    const int srow = src[eblk + t];
    const f32x4* nfr = (const f32x4*)(nf + (srow << 6) + d0base);
#pragma unroll
    for (int q = 0; q < 4; ++q) {
      f32x4 v = nfr[q];
      hs[(q * 4 + 0) * EP + t] = (__bf16)v[0];
      hs[(q * 4 + 1) * EP + t] = (__bf16)v[1];
      hs[(q * 4 + 2) * EP + t] = (__bf16)v[2];
      hs[(q * 4 + 3) * EP + t] = (__bf16)v[3];
    }
  }

  const int w = t >> 6;      // wave id
  const int l = t & 63;      // lane
  const int c = l & 15;
  const int g = l >> 4;

  // A fragments from global EF (bf16 cvt in regs): lane holds A[row = c][k = g*8 + j]
  bf16x8 afr[4];
#pragma unroll
  for (int as = 0; as < 4; ++as) {
    const int e = eblk + w * 64 + as * 16 + c;
    const f32x4* p = (const f32x4*)(ef + (e << 5) + g * 8);
    f32x4 v0 = p[0], v1 = p[1];
    bf16x8 a;
    a[0] = (__bf16)v0[0]; a[1] = (__bf16)v0[1]; a[2] = (__bf16)v0[2]; a[3] = (__bf16)v0[3];
    a[4] = (__bf16)v1[0]; a[5] = (__bf16)v1[1]; a[6] = (__bf16)v1[2]; a[7] = (__bf16)v1[3];
    afr[as] = a;
  }

  __syncthreads();

  f32x4 acc[4][4];
#pragma unroll
  for (int i = 0; i < 4; ++i)
#pragma unroll
    for (int j = 0; j < 4; ++j) {
      acc[i][j][0] = 0.f; acc[i][j][1] = 0.f; acc[i][j][2] = 0.f; acc[i][j][3] = 0.f;
    }

  const bf16x8* WpV = (const bf16x8*)Wp;

#pragma unroll 2
  for (int dl = 0; dl < 16; ++dl) {
    const int d0 = d0base + dl;
    bf16x8 bfr[4];
    f32x4 cb[4];
#pragma unroll
    for (int ht = 0; ht < 4; ++ht) {
      const int T = d0 * 4 + ht;
      bfr[ht] = WpV[T * 64 + l];
      const float bv = bp[T * 16 + c];
      cb[ht][0] = bv; cb[ht][1] = bv; cb[ht][2] = bv; cb[ht][3] = bv;
    }
#pragma unroll
    for (int as = 0; as < 4; ++as) {
      bf16x4 hv = *(const bf16x4*)&hs[dl * EP + w * 64 + as * 16 + g * 4];
      const float hf0 = (float)hv[0], hf1 = (float)hv[1];
      const float hf2 = (float)hv[2], hf3 = (float)hv[3];
#pragma unroll
      for (int ht = 0; ht < 4; ++ht) {
        f32x4 tmp = __builtin_amdgcn_mfma_f32_16x16x32_bf16(afr[as], bfr[ht], cb[ht], 0, 0, 0);
        acc[as][ht][0] = fmaf(fmaxf(tmp[0], 0.f), hf0, acc[as][ht][0]);
        acc[as][ht][1] = fmaf(fmaxf(tmp[1], 0.f), hf1, acc[as][ht][1]);
        acc[as][ht][2] = fmaf(fmaxf(tmp[2], 0.f), hf2, acc[as][ht][2]);
        acc[as][ht][3] = fmaf(fmaxf(tmp[3], 0.f), hf3, acc[as][ht][3]);
      }
    }
  }

  // scatter partial m into msum via fp32 atomics; chunk-0 blocks also count edges per dst
#pragma unroll
  for (int as = 0; as < 4; ++as) {
#pragma unroll
    for (int r = 0; r < 4; ++r) {
      const int e = eblk + w * 64 + as * 16 + g * 4 + r;
      const int dd = dst[e];
      float* base = msum + (dd << 6) + c;
      unsafeAtomicAdd(base + 0,  acc[as][0][r]);
      unsafeAtomicAdd(base + 16, acc[as][1][r]);
      unsafeAtomicAdd(base + 32, acc[as][2][r]);
      unsafeAtomicAdd(base + 48, acc[as][3][r]);
      if (chunk == 0 && c == 0) unsafeAtomicAdd(cnt_g + dd, 1.0f);
    }
  }
}

// ---------------- final: out = relu(concat(nf_row, msum_row/cnt) @ Wn + bn) ----------------
// Block: 256 threads = 4 waves, 16 rows per block (4 rows/wave, interleaved for ILP).
// Wn (32 KB) staged in LDS once per block; nf/msum row loads are lane-uniform (scalar).
__global__ __launch_bounds__(256) void final_kernel(
    const float* __restrict__ nf, const float* __restrict__ msum,
    const float* __restrict__ cnt, const float* __restrict__ Wn,
    const float* __restrict__ bn, float* __restrict__ out) {
  __shared__ float wn_s[128 * 64];   // 32 KB
  const int t = threadIdx.x;
#pragma unroll
  for (int i = 0; i < 8; ++i)
    ((f32x4*)wn_s)[i * 256 + t] = ((const f32x4*)Wn)[i * 256 + t];
  __syncthreads();

  const int w = t >> 6, h = t & 63;
  const int row0 = blockIdx.x * 16 + w * 4;
  const float bv = bn[h];
  float acc[4] = {bv, bv, bv, bv};
  float s[4];
#pragma unroll
  for (int i = 0; i < 4; ++i) {
    const float cv = cnt[row0 + i];
    s[i] = cv > 0.f ? 1.f / cv : 0.f;
  }
#pragma unroll 4
  for (int k = 0; k < 64; ++k) {
    const float wv = wn_s[k * 64 + h];
#pragma unroll
    for (int i = 0; i < 4; ++i)
      acc[i] = fmaf(nf[(row0 + i) * 64 + k], wv, acc[i]);
  }
#pragma unroll 4
  for (int k = 0; k < 64; ++k) {
    const float wv = wn_s[(64 + k) * 64 + h];
#pragma unroll
    for (int i = 0; i < 4; ++i)
      acc[i] = fmaf(msum[(row0 + i) * 64 + k] * s[i], wv, acc[i]);
  }
#pragma unroll
  for (int i = 0; i < 4; ++i)
    out[(row0 + i) * 64 + h] = fmaxf(acc[i], 0.f);
}

extern "C" void kernel_launch(void* const* d_in, const int* in_sizes, int n_in,
                              void* d_out, int out_size, void* d_ws, size_t ws_size,
                              hipStream_t stream) {
  const float* nf  = (const float*)d_in[0];
  const float* ef  = (const float*)d_in[1];
  const int*   src = (const int*)d_in[2];
  const int*   dst = (const int*)d_in[3];
  const float* We  = (const float*)d_in[4];
  const float* be  = (const float*)d_in[5];
  const float* Wn  = (const float*)d_in[6];
  const float* bn  = (const float*)d_in[7];
  float* out = (float*)d_out;

  char* ws = (char*)d_ws;
  float* msum = (float*)ws;                               // 8192*64*4 = 2097152 B
  float* cnt  = (float*)(ws + 2097152);                   // 8192*4    = 32768 B
  const size_t need = 2097152 + 32768 + 262144 + 16384;
  __bf16* Wp;
  float*  bp;
  if (ws_size >= need) {
    Wp = (__bf16*)(ws + 2097152 + 32768);                 // 256 KB
    bp = (float*)(ws + 2097152 + 32768 + 262144);         // 16 KB
  } else {
    // fallback: scratch Wp/bp in d_out (fully overwritten by final_kernel afterwards)
    Wp = (__bf16*)d_out;
    bp = (float*)((char*)d_out + 262144);
  }

  hipMemsetAsync(msum, 0, 2097152 + 32768, stream);
  pack_kernel<<<64, 256, 0, stream>>>(We, be, Wp, bp);
  edge_kernel<<<(E_TOT / 256) * DSPLIT, 256, 0, stream>>>(nf, ef, src, dst, Wp, bp, msum, cnt);
  final_kernel<<<NDST / 16, 256, 0, stream>>>(nf, msum, cnt, Wn, bn, out);
}

// Round 3
// 84.975 us; speedup vs baseline: 2.5369x; 2.5369x over previous
//
#include <hip/hip_runtime.h>

// ECConv: out = relu(concat(nf[:8192], mean_seg(relu(EF@We+be).reshape(E,64,64) @ h_src)) @ Wn + bn)
// Sizes: E=65536, N_SRC=32768, N_DST=8192, EDGE_IN=32, NODE_IN=64, HIDDEN=64, cols=4096
// R3: ht-split across waves (64 edges/block, grid 1024, 50% occ), atomics back to 1x (4.2M),
//     packed-f32 epilogue. Lesson R2: device fp32 atomics are memory-side — never multiply them.

typedef float f32x4 __attribute__((ext_vector_type(4)));
typedef __bf16 bf16x8 __attribute__((ext_vector_type(8)));
typedef __bf16 bf16x4 __attribute__((ext_vector_type(4)));

#define E_TOT   65536
#define NDST    8192
#define EPW     72    // hs row pad (bf16 elems)

// ---------------- pack W_e (fp32 [32][4096]) into MFMA-B fragment order, bf16 ----------------
// Tile T = d0*4 + ht covers GEMM cols n = (ht*16 + c)*64 + d0, c=0..15 (16 h at fixed d).
// B frag for mfma_f32_16x16x32_bf16: lane l holds B[k = (l>>4)*8 + j][col = l&15], j=0..7.
__global__ void pack_kernel(const float* __restrict__ We, const float* __restrict__ be,
                            __bf16* __restrict__ Wp, float* __restrict__ bp) {
  int tid = blockIdx.x * 256 + threadIdx.x;       // 16384 threads
  int T = tid >> 6, l = tid & 63;
  int d0 = T >> 2, ht = T & 3;
  int c = l & 15, kg = l >> 4;
  int ncol = (ht * 16 + c) * 64 + d0;
  bf16x8 v;
#pragma unroll
  for (int j = 0; j < 8; ++j) {
    int k = kg * 8 + j;
    v[j] = (__bf16)We[k * 4096 + ncol];
  }
  *reinterpret_cast<bf16x8*>(Wp + tid * 8) = v;
  if (l < 16) bp[T * 16 + l] = be[(ht * 16 + l) * 64 + d0];
}

// ---------------- main fused edge kernel ----------------
// Block: 256 threads = 4 waves; block covers 64 edges; wave w owns h-quadrant ht = w.
// Per wave: loop d0=0..63 { 1 B-frag load, 4 MFMAs (as=0..3, 16 edges each), pk epilogue }.
// Lane's acc[as][r] == m[edge = eblk + as*16 + g*4 + r][h = w*16 + c] (final, no reduce).
__global__ __launch_bounds__(256, 4) void edge_kernel(
    const float* __restrict__ nf, const float* __restrict__ ef,
    const int* __restrict__ src, const int* __restrict__ dst,
    const __bf16* __restrict__ Wp, const float* __restrict__ bp,
    float* __restrict__ msum, float* __restrict__ cnt_g) {
  __shared__ __bf16 hs[64 * EPW];   // transposed: hs[d][e_local], 9.2 KB
  const int t = threadIdx.x;
  const int eblk = blockIdx.x << 6;

  // stage h_src transposed: thread t -> edge el = t&63, d-quarter q = t>>6 (16 d values)
  {
    const int el = t & 63, q = t >> 6;
    const int srow = src[eblk + el];
    const f32x4* nfr = (const f32x4*)(nf + (srow << 6) + (q << 4));
#pragma unroll
    for (int i = 0; i < 4; ++i) {
      f32x4 v = nfr[i];
      const int dbase = (q << 4) + i * 4;
      hs[(dbase + 0) * EPW + el] = (__bf16)v[0];
      hs[(dbase + 1) * EPW + el] = (__bf16)v[1];
      hs[(dbase + 2) * EPW + el] = (__bf16)v[2];
      hs[(dbase + 3) * EPW + el] = (__bf16)v[3];
    }
  }

  const int w = t >> 6;      // wave id == ht quadrant
  const int l = t & 63;
  const int c = l & 15;
  const int g = l >> 4;

  // A fragments (all 64 block edges): lane holds A[row = c][k = g*8 + j]
  bf16x8 afr[4];
#pragma unroll
  for (int as = 0; as < 4; ++as) {
    const int e = eblk + as * 16 + c;
    const f32x4* p = (const f32x4*)(ef + (e << 5) + (g << 3));
    f32x4 v0 = p[0], v1 = p[1];
    bf16x8 a;
    a[0] = (__bf16)v0[0]; a[1] = (__bf16)v0[1]; a[2] = (__bf16)v0[2]; a[3] = (__bf16)v0[3];
    a[4] = (__bf16)v1[0]; a[5] = (__bf16)v1[1]; a[6] = (__bf16)v1[2]; a[7] = (__bf16)v1[3];
    afr[as] = a;
  }

  __syncthreads();

  f32x4 acc[4];
#pragma unroll
  for (int i = 0; i < 4; ++i) { acc[i][0] = 0.f; acc[i][1] = 0.f; acc[i][2] = 0.f; acc[i][3] = 0.f; }

  const bf16x8* WpV = (const bf16x8*)Wp;
  const f32x4 zero = {0.f, 0.f, 0.f, 0.f};

#pragma unroll 4
  for (int d0 = 0; d0 < 64; ++d0) {
    const int T = d0 * 4 + w;
    const bf16x8 bfr = WpV[T * 64 + l];
    const float bv = bp[T * 16 + c];
    const f32x4 cb = {bv, bv, bv, bv};
#pragma unroll
    for (int as = 0; as < 4; ++as) {
      const bf16x4 hv = *(const bf16x4*)&hs[d0 * EPW + as * 16 + (g << 2)];
      const f32x4 hvf = {(float)hv[0], (float)hv[1], (float)hv[2], (float)hv[3]};
      f32x4 tmp = __builtin_amdgcn_mfma_f32_16x16x32_bf16(afr[as], bfr, cb, 0, 0, 0);
      tmp = __builtin_elementwise_max(tmp, zero);   // relu  (v_pk_max_f32)
      acc[as] = tmp * hvf + acc[as];                // einsum (v_pk_fma_f32)
    }
  }

  // scatter m into msum via fp32 atomics; per instr: 4 edges x 16 consecutive h = 4x64B segments
#pragma unroll
  for (int as = 0; as < 4; ++as) {
#pragma unroll
    for (int r = 0; r < 4; ++r) {
      const int e = eblk + as * 16 + (g << 2) + r;
      const int dd = dst[e];
      unsafeAtomicAdd(msum + (dd << 6) + (w << 4) + c, acc[as][r]);
      if (w == 0 && c == 0) unsafeAtomicAdd(cnt_g + dd, 1.0f);
    }
  }
}

// ---------------- final: out = relu(concat(nf_row, msum_row/cnt) @ Wn + bn) ----------------
// Block: 256 threads = 4 waves, 16 rows per block (4 rows/wave). Wn (32 KB) staged in LDS.
__global__ __launch_bounds__(256) void final_kernel(
    const float* __restrict__ nf, const float* __restrict__ msum,
    const float* __restrict__ cnt, const float* __restrict__ Wn,
    const float* __restrict__ bn, float* __restrict__ out) {
  __shared__ float wn_s[128 * 64];   // 32 KB
  const int t = threadIdx.x;
#pragma unroll
  for (int i = 0; i < 8; ++i)
    ((f32x4*)wn_s)[i * 256 + t] = ((const f32x4*)Wn)[i * 256 + t];
  __syncthreads();

  const int w = t >> 6, h = t & 63;
  const int row0 = blockIdx.x * 16 + w * 4;
  const float bv = bn[h];
  float acc[4] = {bv, bv, bv, bv};
  float s[4];
#pragma unroll
  for (int i = 0; i < 4; ++i) {
    const float cv = cnt[row0 + i];
    s[i] = cv > 0.f ? 1.f / cv : 0.f;
  }
#pragma unroll 4
  for (int k = 0; k < 64; ++k) {
    const float wv = wn_s[k * 64 + h];
#pragma unroll
    for (int i = 0; i < 4; ++i)
      acc[i] = fmaf(nf[(row0 + i) * 64 + k], wv, acc[i]);
  }
#pragma unroll 4
  for (int k = 0; k < 64; ++k) {
    const float wv = wn_s[(64 + k) * 64 + h];
#pragma unroll
    for (int i = 0; i < 4; ++i)
      acc[i] = fmaf(msum[(row0 + i) * 64 + k] * s[i], wv, acc[i]);
  }
#pragma unroll
  for (int i = 0; i < 4; ++i)
    out[(row0 + i) * 64 + h] = fmaxf(acc[i], 0.f);
}

extern "C" void kernel_launch(void* const* d_in, const int* in_sizes, int n_in,
                              void* d_out, int out_size, void* d_ws, size_t ws_size,
                              hipStream_t stream) {
  const float* nf  = (const float*)d_in[0];
  const float* ef  = (const float*)d_in[1];
  const int*   src = (const int*)d_in[2];
  const int*   dst = (const int*)d_in[3];
  const float* We  = (const float*)d_in[4];
  const float* be  = (const float*)d_in[5];
  const float* Wn  = (const float*)d_in[6];
  const float* bn  = (const float*)d_in[7];
  float* out = (float*)d_out;

  char* ws = (char*)d_ws;
  float* msum = (float*)ws;                               // 8192*64*4 = 2097152 B
  float* cnt  = (float*)(ws + 2097152);                   // 8192*4    = 32768 B
  const size_t need = 2097152 + 32768 + 262144 + 16384;
  __bf16* Wp;
  float*  bp;
  if (ws_size >= need) {
    Wp = (__bf16*)(ws + 2097152 + 32768);                 // 256 KB
    bp = (float*)(ws + 2097152 + 32768 + 262144);         // 16 KB
  } else {
    // fallback: scratch Wp/bp in d_out (fully overwritten by final_kernel afterwards)
    Wp = (__bf16*)d_out;
    bp = (float*)((char*)d_out + 262144);
  }

  hipMemsetAsync(msum, 0, 2097152 + 32768, stream);
  pack_kernel<<<64, 256, 0, stream>>>(We, be, Wp, bp);
  edge_kernel<<<E_TOT / 64, 256, 0, stream>>>(nf, ef, src, dst, Wp, bp, msum, cnt);
  final_kernel<<<NDST / 16, 256, 0, stream>>>(nf, msum, cnt, Wn, bn, out);
}